// Round 1
// baseline (368.556 us; speedup 1.0000x reference)
//
#include <hip/hip_runtime.h>

typedef unsigned short u16;
typedef unsigned int u32;
typedef float f32x4 __attribute__((ext_vector_type(4)));
typedef __bf16 bf16x8 __attribute__((ext_vector_type(8)));

#define T_TOK 4096
#define HDIM 1024
#define IDIM 512
#define NEXP 32
#define KSEL 8
#define CAPE 2048
#define NROW (NEXP*CAPE + T_TOK)   // 69632 rows total (experts + shared)

__device__ __forceinline__ u16 f32_to_bf16(float f) {
  u32 x = __float_as_uint(f);
  u32 r = (x + 0x7FFFu + ((x >> 16) & 1u)) >> 16;   // RNE; inputs finite
  return (u16)r;
}
__device__ __forceinline__ float bf16_to_f32(u16 u) {
  return __uint_as_float(((u32)u) << 16);
}

// ---------------- fp32 -> bf16 plain convert (n8 = count of 8-elem chunks) ----------------
__global__ __launch_bounds__(256) void k_cvt(const float* __restrict__ src, u16* __restrict__ dst, long n8) {
  long i = blockIdx.x * 256L + threadIdx.x;
  long stride = (long)gridDim.x * 256L;
  for (long j = i; j < n8; j += stride) {
    float4 a = reinterpret_cast<const float4*>(src)[2*j];
    float4 b = reinterpret_cast<const float4*>(src)[2*j+1];
    ushort4 lo, hi;
    lo.x=f32_to_bf16(a.x); lo.y=f32_to_bf16(a.y); lo.z=f32_to_bf16(a.z); lo.w=f32_to_bf16(a.w);
    hi.x=f32_to_bf16(b.x); hi.y=f32_to_bf16(b.y); hi.z=f32_to_bf16(b.z); hi.w=f32_to_bf16(b.w);
    reinterpret_cast<ushort4*>(dst)[2*j]   = lo;
    reinterpret_cast<ushort4*>(dst)[2*j+1] = hi;
  }
}

// ---------------- w13 convert with 16-row w1/w3 interleave ----------------
// dest row rd (0..1023 per expert): chunk c=rd>>4; c even -> w1 rows (c>>1)*16.., c odd -> w3 rows.
// So h13 col-block 2p holds h1 cols p*16.. and col-block 2p+1 holds h3 cols p*16..
__global__ __launch_bounds__(256) void k_cvt_w13(const float* __restrict__ src1, const float* __restrict__ src3,
                                                 u16* __restrict__ dst, int nexp, long sstride) {
  long n8 = (long)nexp * 1024 * 128;
  long i = blockIdx.x * 256L + threadIdx.x;
  long stride = (long)gridDim.x * 256L;
  for (long j = i; j < n8; j += stride) {
    int e   = (int)(j >> 17);
    int rem = (int)(j & 131071);
    int rowd = rem >> 7;
    int c8   = rem & 127;
    int c = rowd >> 4, cw = rowd & 15;
    int srow = (c >> 1) * 16 + cw;
    const float* s = ((c & 1) ? src3 : src1) + (long)e * sstride + (long)srow * HDIM + c8 * 8;
    float4 a = reinterpret_cast<const float4*>(s)[0];
    float4 b = reinterpret_cast<const float4*>(s)[1];
    ushort4 lo, hi;
    lo.x=f32_to_bf16(a.x); lo.y=f32_to_bf16(a.y); lo.z=f32_to_bf16(a.z); lo.w=f32_to_bf16(a.w);
    hi.x=f32_to_bf16(b.x); hi.y=f32_to_bf16(b.y); hi.z=f32_to_bf16(b.z); hi.w=f32_to_bf16(b.w);
    u16* d = dst + ((long)e * 1024 + rowd) * HDIM + c8 * 8;
    reinterpret_cast<ushort4*>(d)[0] = lo;
    reinterpret_cast<ushort4*>(d)[1] = hi;
  }
}

// ---------------- gating: fp64 scores + group-limited top-k ----------------
__global__ __launch_bounds__(256) void k_gate(const float* __restrict__ x, const float* __restrict__ gw,
                                              int* __restrict__ idx, float* __restrict__ wts) {
  __shared__ float xs[32][129];
  __shared__ float gs_[32][129];
  __shared__ double sc[32][32];
  const int tid = threadIdx.x;
  const int t0 = blockIdx.x * 32;
  const int tl = tid & 31, g = tid >> 5;   // token-local, expert-group
  double acc0 = 0, acc1 = 0, acc2 = 0, acc3 = 0;
  for (int k0 = 0; k0 < HDIM; k0 += 128) {
#pragma unroll
    for (int q = 0; q < 4; ++q) {
      int f = tid + 256 * q;               // 1024 float4 chunks
      int row = f >> 5, c4 = (f & 31) * 4;
      float4 v = *reinterpret_cast<const float4*>(x + (long)(t0 + row) * HDIM + k0 + c4);
      xs[row][c4+0]=v.x; xs[row][c4+1]=v.y; xs[row][c4+2]=v.z; xs[row][c4+3]=v.w;
      float4 w = *reinterpret_cast<const float4*>(gw + (long)row * HDIM + k0 + c4);
      gs_[row][c4+0]=w.x; gs_[row][c4+1]=w.y; gs_[row][c4+2]=w.z; gs_[row][c4+3]=w.w;
    }
    __syncthreads();
#pragma unroll 4
    for (int kk = 0; kk < 128; ++kk) {
      double xv = (double)xs[tl][kk];
      acc0 += xv * (double)gs_[g     ][kk];
      acc1 += xv * (double)gs_[g +  8][kk];
      acc2 += xv * (double)gs_[g + 16][kk];
      acc3 += xv * (double)gs_[g + 24][kk];
    }
    __syncthreads();
  }
  sc[tl][g     ] = 1.0 / (1.0 + exp(-acc0));
  sc[tl][g +  8] = 1.0 / (1.0 + exp(-acc1));
  sc[tl][g + 16] = 1.0 / (1.0 + exp(-acc2));
  sc[tl][g + 24] = 1.0 / (1.0 + exp(-acc3));
  __syncthreads();
  if (tid < 32) {
    int t = t0 + tid;
    double gsc[8];
#pragma unroll
    for (int gg = 0; gg < 8; ++gg) {
      double mx = sc[tid][4*gg];
#pragma unroll
      for (int j = 1; j < 4; ++j) mx = fmax(mx, sc[tid][4*gg + j]);
      gsc[gg] = mx;
    }
    unsigned gmask = 0;
    for (int it = 0; it < 4; ++it) {          // top-4 groups, strict >, first index wins
      double best = -1e300; int bi = 0;
      for (int gg = 0; gg < 8; ++gg)
        if (!((gmask >> gg) & 1) && gsc[gg] > best) { best = gsc[gg]; bi = gg; }
      gmask |= 1u << bi;
    }
    unsigned emask = 0; int ei[KSEL]; double ew[KSEL]; double wsum = 0;
    for (int it = 0; it < KSEL; ++it) {       // top-8 experts within selected groups
      double best = -1e300; int bi = 0;
      for (int e = 0; e < NEXP; ++e)
        if (((gmask >> (e >> 2)) & 1) && !((emask >> e) & 1)) {
          double v = sc[tid][e];
          if (v > best) { best = v; bi = e; }
        }
      emask |= 1u << bi; ei[it] = bi; ew[it] = best; wsum += best;
    }
    double s = 2.5 / (wsum + 1e-20);
    for (int k = 0; k < KSEL; ++k) { idx[t*KSEL + k] = ei[k]; wts[t*KSEL + k] = (float)(ew[k] * s); }
  }
}

// ---------------- capacity assignment: per-expert ordered scan ----------------
__global__ __launch_bounds__(256) void k_assign(const int* __restrict__ idx,
                                                int* __restrict__ etok, int* __restrict__ pos,
                                                int* __restrict__ cnts) {
  const int e = blockIdx.x;
  const int tid = threadIdx.x;
  if (e == NEXP) {                               // shared "expert": identity token list
    for (int t = tid; t < T_TOK; t += 256) etok[NEXP*CAPE + t] = t;
    if (tid == 0) cnts[NEXP] = T_TOK;
    return;
  }
  __shared__ int scan[256];
  int base = 0;
  for (int t0 = 0; t0 < T_TOK; t0 += 256) {
    int t = t0 + tid;
    int found = -1;
#pragma unroll
    for (int k = 0; k < KSEL; ++k) if (idx[t*KSEL + k] == e) found = k;
    int flag = (found >= 0) ? 1 : 0;
    __syncthreads();
    scan[tid] = flag;
    __syncthreads();
    for (int off = 1; off < 256; off <<= 1) {
      int v = scan[tid];
      int add = (tid >= off) ? scan[tid - off] : 0;
      __syncthreads();
      scan[tid] = v + add;
      __syncthreads();
    }
    int incl = scan[tid];
    int total = scan[255];
    if (flag) {
      int slot = base + incl - 1;                // exclusive rank in token order
      pos[t*KSEL + found] = slot;
      if (slot < CAPE) etok[e*CAPE + slot] = t;
    }
    base += total;
  }
  if (tid == 0) cnts[e] = min(base, CAPE);
}

// ---------------- grouped GEMM: 128x128 tile, BK=64, global_load_lds + XOR swizzle ----------------
#define GLDS(gp, lp) __builtin_amdgcn_global_load_lds( \
    (const __attribute__((address_space(1))) void*)(gp), \
    (__attribute__((address_space(3))) void*)(lp), 16, 0, 0)

template<int KDIM, bool GATHER, bool ACT>
__global__ __launch_bounds__(256) void k_gemm(const u16* __restrict__ A, const u16* __restrict__ Ball,
                                              u16* __restrict__ out,
                                              const int* __restrict__ etok, const int* __restrict__ cnts) {
  __shared__ u16 lA[128 * 64];
  __shared__ u16 lB[128 * 64];
  const int e = blockIdx.z;
  const int cnt = cnts[e];
  const int brow = blockIdx.y * 128;
  if (brow >= cnt) return;
  const int rv = min(128, cnt - brow);
  const long rowbase = (long)e * CAPE;                 // also = 65536 for e==32 (shared)
  const u16* Bexp = Ball + (size_t)e * (size_t)(1024 * KDIM);

  const int tid = threadIdx.x;
  const int wave = tid >> 6, lane = tid & 63;
  const int wr = wave >> 1, wc = wave & 1;

  // staging source pointers: chunk ci = (wave*4+c)*64+lane; row=ci>>3, slot=ci&7; source col pre-swizzled
  const u16* pA[4]; const u16* pB[4];
#pragma unroll
  for (int c = 0; c < 4; ++c) {
    int ci = (wave*4 + c) * 64 + lane;
    int row = ci >> 3, slot = ci & 7;
    int sl = slot ^ (row & 7);
    long arow;
    if (GATHER) arow = (row < rv) ? (long)etok[rowbase + brow + row] : 0L;
    else        arow = rowbase + brow + row;           // in-bounds even past cnt (masked at store)
    pA[c] = A + arow * KDIM + sl * 8;
    pB[c] = Bexp + ((long)blockIdx.x * 128 + row) * KDIM + sl * 8;
  }

  f32x4 zero = {0.f, 0.f, 0.f, 0.f};
  f32x4 acc[4][4];
#pragma unroll
  for (int m = 0; m < 4; ++m)
#pragma unroll
    for (int n = 0; n < 4; ++n) acc[m][n] = zero;

  for (int kt = 0; kt < KDIM / 64; ++kt) {
#pragma unroll
    for (int c = 0; c < 4; ++c) GLDS(pA[c] + kt*64, lA + (wave*4 + c) * 512);
#pragma unroll
    for (int c = 0; c < 4; ++c) GLDS(pB[c] + kt*64, lB + (wave*4 + c) * 512);
    __syncthreads();                                   // compiler drains vmcnt before barrier
#pragma unroll
    for (int kk = 0; kk < 2; ++kk) {
      bf16x8 af[4], bfr[4];
#pragma unroll
      for (int m = 0; m < 4; ++m) {
        int r = wr*64 + m*16 + (lane & 15);
        int bc = (kk*64 + ((lane >> 4) * 16)) ^ ((r & 7) << 4);
        af[m] = *reinterpret_cast<const bf16x8*>(reinterpret_cast<const char*>(lA) + r*128 + bc);
      }
#pragma unroll
      for (int n = 0; n < 4; ++n) {
        int r = wc*64 + n*16 + (lane & 15);
        int bc = (kk*64 + ((lane >> 4) * 16)) ^ ((r & 7) << 4);
        bfr[n] = *reinterpret_cast<const bf16x8*>(reinterpret_cast<const char*>(lB) + r*128 + bc);
      }
#pragma unroll
      for (int m = 0; m < 4; ++m)
#pragma unroll
        for (int n = 0; n < 4; ++n)
          acc[m][n] = __builtin_amdgcn_mfma_f32_16x16x32_bf16(af[m], bfr[n], acc[m][n], 0, 0, 0);
    }
    __syncthreads();
  }

  // epilogue: C/D map col=lane&15, row=(lane>>4)*4+reg  [verified m89]
  if (ACT) {
#pragma unroll
    for (int m = 0; m < 4; ++m) {
#pragma unroll
      for (int q = 0; q < 2; ++q) {
        f32x4 h1 = acc[m][2*q], h3 = acc[m][2*q + 1];
        int ucol = blockIdx.x*64 + wc*32 + q*16 + (lane & 15);
#pragma unroll
        for (int j = 0; j < 4; ++j) {
          int lrow = wr*64 + m*16 + ((lane >> 4) << 2) + j;
          if (lrow < rv) {
            float v1 = h1[j];
            float uu = v1 / (1.f + __expf(-v1)) * h3[j];   // silu(h1)*h3
            out[(size_t)(rowbase + brow + lrow) * IDIM + ucol] = f32_to_bf16(uu);
          }
        }
      }
    }
  } else {
#pragma unroll
    for (int m = 0; m < 4; ++m) {
#pragma unroll
      for (int n = 0; n < 4; ++n) {
        int col = blockIdx.x*128 + wc*64 + n*16 + (lane & 15);
#pragma unroll
        for (int j = 0; j < 4; ++j) {
          int lrow = wr*64 + m*16 + ((lane >> 4) << 2) + j;
          if (lrow < rv)
            out[(size_t)(rowbase + brow + lrow) * HDIM + col] = f32_to_bf16(acc[m][n][j]);
        }
      }
    }
  }
}

// ---------------- combine: y[t] = sum_k w_k * oe[e_k][pos_k] + shared[t] ----------------
__global__ __launch_bounds__(256) void k_combine(const u16* __restrict__ oe,
                                                 const int* __restrict__ idx, const float* __restrict__ wts,
                                                 const int* __restrict__ pos, float* __restrict__ y) {
  int t = blockIdx.x;
  int h0 = threadIdx.x * 4;
  float a0 = 0, a1 = 0, a2 = 0, a3 = 0;
#pragma unroll
  for (int k = 0; k < KSEL; ++k) {
    int e = idx[t*KSEL + k];
    int p = pos[t*KSEL + k];
    if (p < CAPE) {
      float w = wts[t*KSEL + k];
      ushort4 v = *reinterpret_cast<const ushort4*>(oe + ((long)e * CAPE + p) * HDIM + h0);
      a0 += w * bf16_to_f32(v.x); a1 += w * bf16_to_f32(v.y);
      a2 += w * bf16_to_f32(v.z); a3 += w * bf16_to_f32(v.w);
    }
  }
  ushort4 s = *reinterpret_cast<const ushort4*>(oe + ((long)NEXP * CAPE + t) * HDIM + h0);
  a0 += bf16_to_f32(s.x); a1 += bf16_to_f32(s.y); a2 += bf16_to_f32(s.z); a3 += bf16_to_f32(s.w);
  float4 o; o.x = a0; o.y = a1; o.z = a2; o.w = a3;
  reinterpret_cast<float4*>(y + (long)t * HDIM)[threadIdx.x] = o;
}

extern "C" void kernel_launch(void* const* d_in, const int* in_sizes, int n_in,
                              void* d_out, int out_size, void* d_ws, size_t ws_size,
                              hipStream_t stream) {
  const float* x      = (const float*)d_in[0];
  const float* gate_w = (const float*)d_in[1];
  const float* w13    = (const float*)d_in[2];
  const float* w2     = (const float*)d_in[3];
  const float* sw1    = (const float*)d_in[4];
  const float* sw2    = (const float*)d_in[5];
  const float* sw3    = (const float*)d_in[6];
  float* y = (float*)d_out;

  char* base = (char*)d_ws;
  size_t off = 0;
  auto alloc = [&](size_t bytes) -> void* {
    void* p = base + off;
    off = (off + bytes + 255) & ~(size_t)255;
    return p;
  };
  u16* xb    = (u16*)alloc((size_t)T_TOK * HDIM * 2);
  u16* w13b  = (u16*)alloc((size_t)(NEXP + 1) * 2 * IDIM * HDIM * 2);
  u16* w2b   = (u16*)alloc((size_t)(NEXP + 1) * HDIM * IDIM * 2);
  u16* u_ws  = (u16*)alloc((size_t)NROW * IDIM * 2);
  u16* oe_ws = (u16*)alloc((size_t)NROW * HDIM * 2);
  int*   idx  = (int*)alloc((size_t)T_TOK * KSEL * 4);
  float* wts  = (float*)alloc((size_t)T_TOK * KSEL * 4);
  int*   pos  = (int*)alloc((size_t)T_TOK * KSEL * 4);
  int*   etok = (int*)alloc((size_t)NROW * 4);
  int*   cnts = (int*)alloc(256);
  if (off > ws_size) return;   // workspace too small (expect ~327 MB)

  // converts (bf16): x, w2 (+sw2 appended as expert 32), w13 interleaved (+sw1/sw3 as expert 32)
  k_cvt<<<dim3(2048), dim3(256), 0, stream>>>(x, xb, (long)T_TOK * HDIM / 8);
  k_cvt<<<dim3(2048), dim3(256), 0, stream>>>(w2, w2b, (long)NEXP * HDIM * IDIM / 8);
  k_cvt<<<dim3(256),  dim3(256), 0, stream>>>(sw2, w2b + (size_t)NEXP * HDIM * IDIM, (long)HDIM * IDIM / 8);
  k_cvt_w13<<<dim3(2048), dim3(256), 0, stream>>>(w13, w13 + (size_t)IDIM * HDIM, w13b, NEXP, (long)2 * IDIM * HDIM);
  k_cvt_w13<<<dim3(512),  dim3(256), 0, stream>>>(sw1, sw3, w13b + (size_t)NEXP * 2 * IDIM * HDIM, 1, 0L);

  k_gate<<<dim3(T_TOK / 32), dim3(256), 0, stream>>>(x, gate_w, idx, wts);
  k_assign<<<dim3(NEXP + 1), dim3(256), 0, stream>>>(idx, etok, pos, cnts);

  k_gemm<HDIM, true,  true ><<<dim3(8, 32, NEXP + 1), dim3(256), 0, stream>>>(xb,   w13b, u_ws,  etok, cnts);
  k_gemm<IDIM, false, false><<<dim3(8, 32, NEXP + 1), dim3(256), 0, stream>>>(u_ws, w2b,  oe_ws, etok, cnts);

  k_combine<<<dim3(T_TOK), dim3(256), 0, stream>>>(oe_ws, idx, wts, pos, y);
}